// Round 21
// baseline (397.159 us; speedup 1.0000x reference)
//
#include <hip/hip_runtime.h>
#include <hip/hip_bf16.h>
#include <cstdint>

#define BB 128
#define LL 256
#define DD 300
#define HH 512
#define TOUT 511
#define NGATE 2560   // 5*H

typedef __attribute__((ext_vector_type(8))) short bf16x8;
typedef __attribute__((ext_vector_type(4))) float f32x4;

__device__ __forceinline__ float rcpf(float x){ return __builtin_amdgcn_rcpf(x); }
__device__ __forceinline__ float ex2f(float x){ return __builtin_amdgcn_exp2f(x); }
__device__ __forceinline__ float sigf(float x){ return rcpf(1.0f + ex2f(x * -1.44269504f)); }
__device__ __forceinline__ float tanh_fast(float x){ return 1.0f - 2.0f*rcpf(ex2f(x * 2.88539008f) + 1.0f); }

__device__ __forceinline__ void load_lds16(const void* g, void* l) {
  __builtin_amdgcn_global_load_lds(
      (const __attribute__((address_space(1))) unsigned int*)g,
      (__attribute__((address_space(3))) unsigned int*)l, 16, 0, 0);
}

#define VMWAIT(n) asm volatile("s_waitcnt vmcnt(" #n ")" ::: "memory")
#define LGKM0()   asm volatile("s_waitcnt lgkmcnt(0)" ::: "memory")

// ---- fused weight prep
__global__ __launch_bounds__(256) void prep_weights(
    const float* __restrict__ Wx, const float* __restrict__ Ul, const float* __restrict__ Ur,
    __hip_bfloat16* __restrict__ Wb0t, __hip_bfloat16* __restrict__ Wb1t)
{
  const int z = blockIdx.z;
  const float* src; __hip_bfloat16* dst; int Ksrc, Kdst, koff;
  if (z == 0) { if (blockIdx.x >= 5) return; src = Wx; dst = Wb0t; Ksrc = DD; Kdst = 320; koff = 0; }
  else if (z == 1) { src = Ul; dst = Wb1t; Ksrc = HH; Kdst = 1024; koff = 0; }
  else { src = Ur; dst = Wb1t; Ksrc = HH; Kdst = 1024; koff = 512; }

  __shared__ float t[64][65];
  const int tid = threadIdx.x;
  const int k0 = blockIdx.x * 64;
  const int n0 = blockIdx.y * 64;
  #pragma unroll
  for (int p = 0; p < 16; ++p) {
    int lin = p*256 + tid;
    int ki = lin >> 6, nj = lin & 63;
    t[ki][nj] = (k0 + ki < Ksrc) ? src[(size_t)(k0+ki)*NGATE + n0 + nj] : 0.f;
  }
  __syncthreads();
  #pragma unroll
  for (int p = 0; p < 16; ++p) {
    int lin = p*256 + tid;
    int ni = lin >> 6, kj = lin & 63;
    dst[(size_t)(n0+ni)*Kdst + koff + k0 + kj] = __float2bfloat16(t[kj][ni]);
  }
}

// ---- embedding gather + cvt, vectorized (bf16x8 per thread)
__global__ __launch_bounds__(256) void embed_cvt(
    const int* __restrict__ tok, const float* __restrict__ emb,
    __hip_bfloat16* __restrict__ A0)
{
  int idx = blockIdx.x*256 + threadIdx.x;
  int r  = idx / 40;
  int ck = (idx - r*40) * 8;
  int tk = tok[r];
  const float* erow = emb + (size_t)tk*DD;
  float v[8];
  if (ck + 8 <= DD) {
    float4 lo = *reinterpret_cast<const float4*>(erow + ck);
    float4 hi = *reinterpret_cast<const float4*>(erow + ck + 4);
    v[0]=lo.x; v[1]=lo.y; v[2]=lo.z; v[3]=lo.w;
    v[4]=hi.x; v[5]=hi.y; v[6]=hi.z; v[7]=hi.w;
  } else {
    #pragma unroll
    for (int j = 0; j < 8; ++j) { int k = ck + j; v[j] = (k < DD) ? erow[k] : 0.f; }
  }
  bf16x8 o;
  #pragma unroll
  for (int j = 0; j < 8; ++j)
    o[j] = (short)__bfloat16_as_ushort(__float2bfloat16(v[j]));
  *reinterpret_cast<bf16x8*>(&A0[(size_t)r*320 + ck]) = o;
}

// ======== L0 kernel: R13 tail body at K=320 (BM=128, BK=64, nk=5, no cprev).
// 2048 blocks, 8 short chains/CU with dispatch backfill (the tail regime).
__global__ __launch_bounds__(512, 2) void gemm_tail0(
    const __hip_bfloat16* __restrict__ A, const __hip_bfloat16* __restrict__ Wt,
    const float* __restrict__ bias,
    float* __restrict__ out, __hip_bfloat16* __restrict__ hout, float* __restrict__ cout)
{
  constexpr int ABYTES = 16384;          // A: 128 x 64k bf16 (128B rows)
  constexpr int BUFS   = ABYTES + 40960; // + B: 320 x 64k bf16
  constexpr size_t rowK = 640;           // K=320 * 2B
  constexpr int NK = 5;
  __shared__ __align__(16) char lds[2*BUFS];

  const int tid  = threadIdx.x;
  const int lane = tid & 63;
  const int wid  = tid >> 6;
  const int wm   = wid >> 2;
  const int wn   = wid & 3;
  const int bid  = blockIdx.x;
  const int m    = (bid & 7) + ((bid >> 6) << 3);   // 0..255 (bijective for 2048)
  const int s    = (bid >> 3) & 7;
  const int r0   = m * 128;
  const int n0   = s * 64;

  const int srow = lane >> 3;
  const int gq   = (lane & 7) ^ srow;
  const char* gsrc[7];
  #pragma unroll
  for (int ii = 0; ii < 7; ++ii) {
    int issue = wid*7 + ii;
    if (issue < 16) {
      int r = issue*8 + srow;
      gsrc[ii] = (const char*)A + (size_t)(r0 + r)*rowK + (size_t)gq*16;
    } else {
      int c = (issue-16)*8 + srow;
      int grow = (c >> 6)*512 + n0 + (c & 63);
      gsrc[ii] = (const char*)Wt + (size_t)grow*rowK + (size_t)gq*16;
    }
  }
  const int ldst0 = (wid*7)*1024 + lane*16;

  f32x4 acc[4][5];
  #pragma unroll
  for (int mf = 0; mf < 4; ++mf)
    #pragma unroll
    for (int g5 = 0; g5 < 5; ++g5)
      acc[mf][g5] = (f32x4){0.f,0.f,0.f,0.f};

  auto stage = [&](int buf, int kt){
    char* base = lds + buf*BUFS + ldst0;
    const size_t kb = (size_t)kt*128;
    #pragma unroll
    for (int ii = 0; ii < 7; ++ii) load_lds16(gsrc[ii] + kb, base + ii*1024);
  };

  stage(0, 0);
  int cur = 0;
  for (int kt = 0; kt < NK; ++kt) {
    if (kt + 1 < NK) {
      stage(cur ^ 1, kt + 1);
      VMWAIT(7);
    } else {
      VMWAIT(0);
    }
    __builtin_amdgcn_s_barrier();

    const char* Ab = lds + cur*BUFS;
    const char* Bb = Ab + ABYTES;
    #pragma unroll
    for (int s2 = 0; s2 < 2; ++s2) {
      const int qb = s2*4 + (lane >> 4);
      bf16x8 b[5];
      #pragma unroll
      for (int g5 = 0; g5 < 5; ++g5) {
        int c = g5*64 + wn*16 + (lane & 15);
        b[g5] = *(const bf16x8*)(Bb + c*128 + ((qb ^ (c & 7))*16));
      }
      __builtin_amdgcn_s_setprio(1);
      #pragma unroll
      for (int mf = 0; mf < 4; ++mf) {
        int r = wm*64 + mf*16 + (lane & 15);
        bf16x8 av = *(const bf16x8*)(Ab + r*128 + ((qb ^ (r & 7))*16));
        #pragma unroll
        for (int g5 = 0; g5 < 5; ++g5)
          acc[mf][g5] = __builtin_amdgcn_mfma_f32_16x16x32_bf16(av, b[g5], acc[mf][g5], 0, 0, 0);
      }
      __builtin_amdgcn_s_setprio(0);
    }
    __builtin_amdgcn_s_barrier();
    cur ^= 1;
  }

  const int jg = n0 + wn*16 + (lane & 15);
  float bia[5];
  #pragma unroll
  for (int g5 = 0; g5 < 5; ++g5) bia[g5] = bias[g5*HH + jg];
  #pragma unroll
  for (int mf = 0; mf < 4; ++mf) {
    #pragma unroll
    for (int v = 0; v < 4; ++v) {
      int rr = r0 + wm*64 + mf*16 + (lane >> 4)*4 + v;
      float gi  = acc[mf][0][v] + bia[0];
      float go  = acc[mf][3][v] + bia[3];
      float gu  = acc[mf][4][v] + bia[4];
      float cc = sigf(gi)*tanh_fast(gu);
      float hh = sigf(go)*tanh_fast(cc);
      int b = rr >> 8;
      int t = rr & 255;
      out[((size_t)b*TOUT + t)*HH + jg] = hh;
      hout[(size_t)rr*HH + jg] = __float2bfloat16(hh);
      cout[(size_t)rr*HH + jg] = cc;
    }
  }
}

// ======== L1/L2 kernel (R7 V_A proven): BM=128, BK=32, 2x28KB, 2 blocks/CU ===
__global__ __launch_bounds__(512, 4) void gemm_cell(
    const __hip_bfloat16* __restrict__ A, const __hip_bfloat16* __restrict__ Wt,
    int K, const float* __restrict__ bias, const float* __restrict__ cprev,
    float* __restrict__ out, __hip_bfloat16* __restrict__ hout, float* __restrict__ cout,
    int lkshift, int sc, int numM)
{
  constexpr int BUFS = 28672;
  __shared__ __align__(16) char lds[2*BUFS];

  const int tid  = threadIdx.x;
  const int lane = tid & 63;
  const int wid  = tid >> 6;
  const int wm   = wid >> 2;
  const int wn   = wid & 3;
  const int bid  = blockIdx.x;
  int m, s;
  if (numM >= 8) { m = (bid & 7) + ((bid >> 6) << 3); s = (bid >> 3) & 7; }
  else           { m = bid % numM;  s = bid / numM; }
  const int r0   = m * 128;
  const int n0   = s * 64;
  const size_t rowK = (size_t)K * 2;

  const char* gsrc[4];
  int gi0 = (wid < 4) ? wid*4 : 16 + (wid-4)*3;
  #pragma unroll
  for (int i = 0; i < 4; ++i) {
    int gi = gi0 + i;
    int row = (gi < 8) ? gi*16 + (lane >> 2) : (gi-8)*16 + (lane >> 2);
    int cs = (lane & 3) ^ ((row >> 1) & 3);
    if (gi < 8) {
      gsrc[i] = (const char*)A + (size_t)(r0 + row)*rowK + cs*16;
    } else {
      int grow = (row >> 6)*512 + n0 + (row & 63);
      gsrc[i] = (const char*)Wt + (size_t)grow*rowK + cs*16;
    }
  }
  const int ldst0 = gi0*1024 + lane*16;

  f32x4 acc[4][5];
  #pragma unroll
  for (int mf = 0; mf < 4; ++mf)
    #pragma unroll
    for (int g5 = 0; g5 < 5; ++g5)
      acc[mf][g5] = (f32x4){0.f,0.f,0.f,0.f};

  const int nk = K >> 5;
  auto stage = [&](int buf, int kt){
    char* base = lds + buf*BUFS + ldst0;
    const size_t kb = (size_t)kt*64;
    if (wid < 4) {
      #pragma unroll
      for (int i = 0; i < 4; ++i) load_lds16(gsrc[i] + kb, base + i*1024);
    } else {
      #pragma unroll
      for (int i = 0; i < 3; ++i) load_lds16(gsrc[i] + kb, base + i*1024);
    }
  };

  stage(0, 0);
  int cur = 0;
  for (int kt = 0; kt < nk; ++kt) {
    if (kt + 1 < nk) {
      stage(cur ^ 1, kt + 1);
      if (wid < 4) VMWAIT(4); else VMWAIT(3);
    } else {
      VMWAIT(0);
    }
    __builtin_amdgcn_s_barrier();

    const char* Ab = lds + cur*BUFS;
    const char* Bb = Ab + 8192;
    const int q = lane >> 4;
    bf16x8 b[5];
    #pragma unroll
    for (int g5 = 0; g5 < 5; ++g5) {
      int c = g5*64 + wn*16 + (lane & 15);
      b[g5] = *(const bf16x8*)(Bb + c*64 + ((q ^ ((c >> 1) & 3))*16));
    }
    __builtin_amdgcn_s_setprio(1);
    #pragma unroll
    for (int mf = 0; mf < 4; ++mf) {
      int r = wm*64 + mf*16 + (lane & 15);
      bf16x8 av = *(const bf16x8*)(Ab + r*64 + ((q ^ ((r >> 1) & 3))*16));
      #pragma unroll
      for (int g5 = 0; g5 < 5; ++g5)
        acc[mf][g5] = __builtin_amdgcn_mfma_f32_16x16x32_bf16(av, b[g5], acc[mf][g5], 0, 0, 0);
    }
    __builtin_amdgcn_s_setprio(0);
    __builtin_amdgcn_s_barrier();
    cur ^= 1;
  }

  const int Lmask = (1 << lkshift) - 1;
  const int jg = n0 + wn*16 + (lane & 15);
  float bia[5];
  #pragma unroll
  for (int g5 = 0; g5 < 5; ++g5) bia[g5] = bias[g5*HH + jg];
  #pragma unroll
  for (int mf = 0; mf < 4; ++mf) {
    #pragma unroll
    for (int v = 0; v < 4; ++v) {
      int rr = r0 + wm*64 + mf*16 + (lane >> 4)*4 + v;
      float gi  = acc[mf][0][v] + bia[0];
      float gfl = acc[mf][1][v] + bia[1];
      float gfr = acc[mf][2][v] + bia[2];
      float go  = acc[mf][3][v] + bia[3];
      float gu  = acc[mf][4][v] + bia[4];
      float cl = cprev[(size_t)(2*rr)*HH + jg];
      float cr = cprev[(size_t)(2*rr)*HH + HH + jg];
      float cc = sigf(gi)*tanh_fast(gu) + sigf(gfl)*cl + sigf(gfr)*cr;
      float hh = sigf(go)*tanh_fast(cc);
      int b = rr >> lkshift;
      int t = rr & Lmask;
      out[((size_t)b*TOUT + sc + t)*HH + jg] = hh;
      hout[(size_t)rr*HH + jg] = __float2bfloat16(hh);
      cout[(size_t)rr*HH + jg] = cc;
    }
  }
}

// ======== TAIL kernel (L3-L8, R13 proven): BM=128, BK=64, 2x56KB dbuf ========
__global__ __launch_bounds__(512, 2) void gemm_tail(
    const __hip_bfloat16* __restrict__ A, const __hip_bfloat16* __restrict__ Wt,
    const float* __restrict__ bias, const float* __restrict__ cprev,
    float* __restrict__ out, __hip_bfloat16* __restrict__ hout, float* __restrict__ cout,
    int lkshift, int sc, int numM)
{
  constexpr int ABYTES = 16384;
  constexpr int BUFS   = ABYTES + 40960;
  __shared__ __align__(16) char lds[2*BUFS];

  const int tid  = threadIdx.x;
  const int lane = tid & 63;
  const int wid  = tid >> 6;
  const int wm   = wid >> 2;
  const int wn   = wid & 3;
  const int bid  = blockIdx.x;
  int m, s;
  if (numM >= 8) { m = (bid & 7) + ((bid >> 6) << 3); s = (bid >> 3) & 7; }
  else           { m = bid % numM;  s = bid / numM; }
  const int r0   = m * 128;
  const int n0   = s * 64;
  constexpr size_t rowK = 2048;

  const int srow = lane >> 3;
  const int gq   = (lane & 7) ^ srow;
  const char* gsrc[7];
  #pragma unroll
  for (int ii = 0; ii < 7; ++ii) {
    int issue = wid*7 + ii;
    if (issue < 16) {
      int r = issue*8 + srow;
      gsrc[ii] = (const char*)A + (size_t)(r0 + r)*rowK + (size_t)gq*16;
    } else {
      int c = (issue-16)*8 + srow;
      int grow = (c >> 6)*512 + n0 + (c & 63);
      gsrc[ii] = (const char*)Wt + (size_t)grow*rowK + (size_t)gq*16;
    }
  }
  const int ldst0 = (wid*7)*1024 + lane*16;

  f32x4 acc[4][5];
  #pragma unroll
  for (int mf = 0; mf < 4; ++mf)
    #pragma unroll
    for (int g5 = 0; g5 < 5; ++g5)
      acc[mf][g5] = (f32x4){0.f,0.f,0.f,0.f};

  auto stage = [&](int buf, int kt){
    char* base = lds + buf*BUFS + ldst0;
    const size_t kb = (size_t)kt*128;
    #pragma unroll
    for (int ii = 0; ii < 7; ++ii) load_lds16(gsrc[ii] + kb, base + ii*1024);
  };

  stage(0, 0);
  int cur = 0;
  for (int kt = 0; kt < 16; ++kt) {
    if (kt + 1 < 16) {
      stage(cur ^ 1, kt + 1);
      VMWAIT(7);
    } else {
      VMWAIT(0);
    }
    __builtin_amdgcn_s_barrier();

    const char* Ab = lds + cur*BUFS;
    const char* Bb = Ab + ABYTES;
    #pragma unroll
    for (int s2 = 0; s2 < 2; ++s2) {
      const int qb = s2*4 + (lane >> 4);
      bf16x8 b[5];
      #pragma unroll
      for (int g5 = 0; g5 < 5; ++g5) {
        int c = g5*64 + wn*16 + (lane & 15);
        b[g5] = *(const bf16x8*)(Bb + c*128 + ((qb ^ (c & 7))*16));
      }
      __builtin_amdgcn_s_setprio(1);
      #pragma unroll
      for (int mf = 0; mf < 4; ++mf) {
        int r = wm*64 + mf*16 + (lane & 15);
        bf16x8 av = *(const bf16x8*)(Ab + r*128 + ((qb ^ (r & 7))*16));
        #pragma unroll
        for (int g5 = 0; g5 < 5; ++g5)
          acc[mf][g5] = __builtin_amdgcn_mfma_f32_16x16x32_bf16(av, b[g5], acc[mf][g5], 0, 0, 0);
      }
      __builtin_amdgcn_s_setprio(0);
    }
    __builtin_amdgcn_s_barrier();
    cur ^= 1;
  }

  const int Lmask = (1 << lkshift) - 1;
  const int jg = n0 + wn*16 + (lane & 15);
  float bia[5];
  #pragma unroll
  for (int g5 = 0; g5 < 5; ++g5) bia[g5] = bias[g5*HH + jg];
  #pragma unroll
  for (int mf = 0; mf < 4; ++mf) {
    #pragma unroll
    for (int v = 0; v < 4; ++v) {
      int rr = r0 + wm*64 + mf*16 + (lane >> 4)*4 + v;
      float gi  = acc[mf][0][v] + bia[0];
      float gfl = acc[mf][1][v] + bia[1];
      float gfr = acc[mf][2][v] + bia[2];
      float go  = acc[mf][3][v] + bia[3];
      float gu  = acc[mf][4][v] + bia[4];
      float cl = cprev[(size_t)(2*rr)*HH + jg];
      float cr = cprev[(size_t)(2*rr)*HH + HH + jg];
      float cc = sigf(gi)*tanh_fast(gu) + sigf(gfl)*cl + sigf(gfr)*cr;
      float hh = sigf(go)*tanh_fast(cc);
      int b = rr >> lkshift;
      int t = rr & Lmask;
      out[((size_t)b*TOUT + sc + t)*HH + jg] = hh;
      hout[(size_t)rr*HH + jg] = __float2bfloat16(hh);
      cout[(size_t)rr*HH + jg] = cc;
    }
  }
}

extern "C" void kernel_launch(void* const* d_in, const int* in_sizes, int n_in,
                              void* d_out, int out_size, void* d_ws, size_t ws_size,
                              hipStream_t stream) {
  (void)in_sizes; (void)n_in; (void)out_size; (void)ws_size;
  const int*   tok  = (const int*)d_in[0];
  const float* emb  = (const float*)d_in[1];
  const float* Wx   = (const float*)d_in[2];
  const float* Ul   = (const float*)d_in[3];
  const float* Ur   = (const float*)d_in[4];
  const float* bias = (const float*)d_in[5];
  float* out = (float*)d_out;

  char* ws = (char*)d_ws;
  size_t off = 0;
  __hip_bfloat16* Wb0t = (__hip_bfloat16*)(ws + off); off += (size_t)NGATE*320*2;
  __hip_bfloat16* Wb1t = (__hip_bfloat16*)(ws + off); off += (size_t)NGATE*1024*2;
  __hip_bfloat16* hA   = (__hip_bfloat16*)(ws + off); off += (size_t)32768*HH*2;
  __hip_bfloat16* hB   = (__hip_bfloat16*)(ws + off); off += (size_t)16384*HH*2;
  float*          cA   = (float*)(ws + off);          off += (size_t)32768*HH*4;
  float*          cB   = (float*)(ws + off);          off += (size_t)16384*HH*4;
  __hip_bfloat16* A0   = (__hip_bfloat16*)cB;   // alias: A0 dead before cB first written

  prep_weights<<<dim3(8, 40, 3), 256, 0, stream>>>(Wx, Ul, Ur, Wb0t, Wb1t);
  embed_cvt<<<(32768*40)/256, 256, 0, stream>>>(tok, emb, A0);

  // level 0: tail-structure A/B (2048 blocks, 8 short chains/CU)
  gemm_tail0<<<2048, 512, 0, stream>>>(A0, Wb0t, bias, out, hA, cA);
  // levels 1-2: R7 gemm_cell, 2 blocks/CU (best measured L1)
  gemm_cell<<<(16384/128)*8, 512, 0, stream>>>(hA, Wb1t, 1024, bias, cA,
                                               out, hB, cB, 7, 256, 16384/128);
  gemm_cell<<<(8192/128)*8, 512, 0, stream>>>(hB, Wb1t, 1024, bias, cB,
                                              out, hA, cA, 6, 384, 8192/128);
  // levels 3..8: R13 BK=64 tail (best measured tail)
  for (int k = 3; k <= 8; ++k) {
    int M = 32768 >> k;
    int sc = HH - (HH >> k);
    const __hip_bfloat16* Ain = (k & 1) ? hA : hB;
    __hip_bfloat16*       hO  = (k & 1) ? hB : hA;
    const float*          cI  = (k & 1) ? cA : cB;
    float*                cO  = (k & 1) ? cB : cA;
    int numM = M / 128;
    gemm_tail<<<numM*8, 512, 0, stream>>>(Ain, Wb1t, bias, cI,
                                          out, hO, cO, 8 - k, sc, numM);
  }
}

// Round 22
// 387.565 us; speedup vs baseline: 1.0248x; 1.0248x over previous
//
#include <hip/hip_runtime.h>
#include <hip/hip_bf16.h>
#include <cstdint>

#define BB 128
#define LL 256
#define DD 300
#define HH 512
#define TOUT 511
#define NGATE 2560   // 5*H

typedef __attribute__((ext_vector_type(8))) short bf16x8;
typedef __attribute__((ext_vector_type(4))) float f32x4;

__device__ __forceinline__ float rcpf(float x){ return __builtin_amdgcn_rcpf(x); }
__device__ __forceinline__ float ex2f(float x){ return __builtin_amdgcn_exp2f(x); }
__device__ __forceinline__ float sigf(float x){ return rcpf(1.0f + ex2f(x * -1.44269504f)); }
__device__ __forceinline__ float tanh_fast(float x){ return 1.0f - 2.0f*rcpf(ex2f(x * 2.88539008f) + 1.0f); }

__device__ __forceinline__ void load_lds16(const void* g, void* l) {
  __builtin_amdgcn_global_load_lds(
      (const __attribute__((address_space(1))) unsigned int*)g,
      (__attribute__((address_space(3))) unsigned int*)l, 16, 0, 0);
}

#define VMWAIT(n) asm volatile("s_waitcnt vmcnt(" #n ")" ::: "memory")
#define LGKM0()   asm volatile("s_waitcnt lgkmcnt(0)" ::: "memory")

// ---- fused weight prep
__global__ __launch_bounds__(256) void prep_weights(
    const float* __restrict__ Wx, const float* __restrict__ Ul, const float* __restrict__ Ur,
    __hip_bfloat16* __restrict__ Wb0t, __hip_bfloat16* __restrict__ Wb1t)
{
  const int z = blockIdx.z;
  const float* src; __hip_bfloat16* dst; int Ksrc, Kdst, koff;
  if (z == 0) { if (blockIdx.x >= 5) return; src = Wx; dst = Wb0t; Ksrc = DD; Kdst = 320; koff = 0; }
  else if (z == 1) { src = Ul; dst = Wb1t; Ksrc = HH; Kdst = 1024; koff = 0; }
  else { src = Ur; dst = Wb1t; Ksrc = HH; Kdst = 1024; koff = 512; }

  __shared__ float t[64][65];
  const int tid = threadIdx.x;
  const int k0 = blockIdx.x * 64;
  const int n0 = blockIdx.y * 64;
  #pragma unroll
  for (int p = 0; p < 16; ++p) {
    int lin = p*256 + tid;
    int ki = lin >> 6, nj = lin & 63;
    t[ki][nj] = (k0 + ki < Ksrc) ? src[(size_t)(k0+ki)*NGATE + n0 + nj] : 0.f;
  }
  __syncthreads();
  #pragma unroll
  for (int p = 0; p < 16; ++p) {
    int lin = p*256 + tid;
    int ni = lin >> 6, kj = lin & 63;
    dst[(size_t)(n0+ni)*Kdst + koff + k0 + kj] = __float2bfloat16(t[kj][ni]);
  }
}

// ---- embedding gather + cvt, vectorized (bf16x8 per thread)
__global__ __launch_bounds__(256) void embed_cvt(
    const int* __restrict__ tok, const float* __restrict__ emb,
    __hip_bfloat16* __restrict__ A0)
{
  int idx = blockIdx.x*256 + threadIdx.x;
  int r  = idx / 40;
  int ck = (idx - r*40) * 8;
  int tk = tok[r];
  const float* erow = emb + (size_t)tk*DD;
  float v[8];
  if (ck + 8 <= DD) {
    float4 lo = *reinterpret_cast<const float4*>(erow + ck);
    float4 hi = *reinterpret_cast<const float4*>(erow + ck + 4);
    v[0]=lo.x; v[1]=lo.y; v[2]=lo.z; v[3]=lo.w;
    v[4]=hi.x; v[5]=hi.y; v[6]=hi.z; v[7]=hi.w;
  } else {
    #pragma unroll
    for (int j = 0; j < 8; ++j) { int k = ck + j; v[j] = (k < DD) ? erow[k] : 0.f; }
  }
  bf16x8 o;
  #pragma unroll
  for (int j = 0; j < 8; ++j)
    o[j] = (short)__bfloat16_as_ushort(__float2bfloat16(v[j]));
  *reinterpret_cast<bf16x8*>(&A0[(size_t)r*320 + ck]) = o;
}

// ======== L0 kernel (R15 proven): persistent panels P=4, NT=10, 4-slot ring ==
__global__ __launch_bounds__(512, 2) void gemm_l0(
    const __hip_bfloat16* __restrict__ A, const __hip_bfloat16* __restrict__ Wt,
    const float* __restrict__ bias,
    float* __restrict__ out, __hip_bfloat16* __restrict__ hout, float* __restrict__ cout)
{
  constexpr int P  = 4;
  constexpr int NT = 10;
  constexpr int HBYT = 36864;
  constexpr size_t rowK = 640;
  constexpr size_t panStride = 256 * rowK;
  __shared__ __align__(16) char lds[4*HBYT];

  const int tid  = threadIdx.x;
  const int lane = tid & 63;
  const int wid  = tid >> 6;
  const int wm   = wid >> 2;
  const int wn   = wid & 3;
  const int bid  = blockIdx.x;
  const int m    = (bid & 7) + ((bid >> 6) << 3);
  const int s    = (bid >> 3) & 7;
  const int n0   = s * 64;

  const bool isAwave = (wid < 4);
  const char* gsrc[5];
  int ldst0;
  if (isAwave) {
    #pragma unroll
    for (int i = 0; i < 4; ++i) {
      int gi  = wid*4 + i;
      int row = gi*16 + (lane >> 2);
      int cs  = (lane & 3) ^ ((row >> 1) & 3);
      gsrc[i] = (const char*)A + (size_t)m*P*panStride + (size_t)row*rowK + cs*16;
    }
    gsrc[4] = nullptr;
    ldst0 = (wid*4)*1024 + lane*16;
  } else {
    #pragma unroll
    for (int i = 0; i < 5; ++i) {
      int bj   = (wid-4)*5 + i;
      int rowb = bj*16 + (lane >> 2);
      int cs   = (lane & 3) ^ ((rowb >> 1) & 3);
      int grow = (rowb >> 6)*512 + n0 + (rowb & 63);
      gsrc[i] = (const char*)Wt + (size_t)grow*rowK + cs*16;
    }
    ldst0 = 16384 + ((wid-4)*5)*1024 + lane*16;
  }

  f32x4 acc[8][5];
  #pragma unroll
  for (int mf = 0; mf < 8; ++mf)
    #pragma unroll
    for (int g5 = 0; g5 < 5; ++g5)
      acc[mf][g5] = (f32x4){0.f,0.f,0.f,0.f};

  int ts = 0, Tstage = 0;
  auto stage = [&](){
    char* base = lds + (size_t)(Tstage & 3)*HBYT + ldst0;
    const size_t kb = (size_t)ts*64;
    if (isAwave) {
      #pragma unroll
      for (int i = 0; i < 4; ++i) load_lds16(gsrc[i] + kb, base + i*1024);
    } else {
      #pragma unroll
      for (int i = 0; i < 5; ++i) load_lds16(gsrc[i] + kb, base + i*1024);
    }
    ++Tstage;
    if (++ts == NT) {
      ts = 0;
      if (isAwave) {
        #pragma unroll
        for (int i = 0; i < 4; ++i) gsrc[i] += panStride;
      }
    }
  };

  stage(); stage(); stage();

  const int jg = n0 + wn*16 + (lane & 15);
  float bia[5];
  #pragma unroll
  for (int g5 = 0; g5 < 5; ++g5) bia[g5] = bias[g5*HH + jg];

  constexpr int total = P * NT;
  #pragma unroll 1
  for (int p = 0; p < P; ++p) {
    #pragma unroll 1
    for (int t = 0; t < NT; ++t) {
      const int Tc = p*NT + t;
      if (Tc + 3 <= total)      { if (isAwave) VMWAIT(8); else VMWAIT(10); }
      else if (Tc + 2 <= total) { if (isAwave) VMWAIT(4); else VMWAIT(5); }
      else                      { VMWAIT(0); }
      LGKM0();
      __builtin_amdgcn_s_barrier();

      const char* Ab = lds + (size_t)(Tc & 3)*HBYT;
      const char* Bb = Ab + 16384;
      const int q = lane >> 4;

      bf16x8 b[5];
      #pragma unroll
      for (int g5 = 0; g5 < 5; ++g5) {
        int c = g5*64 + wn*16 + (lane & 15);
        b[g5] = *(const bf16x8*)(Bb + c*64 + ((q ^ ((c >> 1) & 3))*16));
      }
      bf16x8 a[4];
      #pragma unroll
      for (int i = 0; i < 4; ++i) {
        int r = wm*128 + i*16 + (lane & 15);
        a[i] = *(const bf16x8*)(Ab + r*64 + ((q ^ ((r >> 1) & 3))*16));
      }
      if (Tstage < total) stage();
      __builtin_amdgcn_sched_barrier(0);
      __builtin_amdgcn_s_setprio(1);
      #pragma unroll
      for (int mf = 0; mf < 4; ++mf)
        #pragma unroll
        for (int g5 = 0; g5 < 5; ++g5)
          acc[mf][g5] = __builtin_amdgcn_mfma_f32_16x16x32_bf16(a[mf], b[g5], acc[mf][g5], 0, 0, 0);
      __builtin_amdgcn_s_setprio(0);

      #pragma unroll
      for (int i = 0; i < 4; ++i) {
        int r = wm*128 + (4+i)*16 + (lane & 15);
        a[i] = *(const bf16x8*)(Ab + r*64 + ((q ^ ((r >> 1) & 3))*16));
      }
      __builtin_amdgcn_sched_barrier(0);
      __builtin_amdgcn_s_setprio(1);
      #pragma unroll
      for (int mf = 0; mf < 4; ++mf)
        #pragma unroll
        for (int g5 = 0; g5 < 5; ++g5)
          acc[4+mf][g5] = __builtin_amdgcn_mfma_f32_16x16x32_bf16(a[mf], b[g5], acc[4+mf][g5], 0, 0, 0);
      __builtin_amdgcn_s_setprio(0);
    }

    const int r0 = (m*P + p) * 256;
    #pragma unroll
    for (int mf = 0; mf < 8; ++mf) {
      #pragma unroll
      for (int v = 0; v < 4; ++v) {
        int rr = r0 + wm*128 + mf*16 + (lane >> 4)*4 + v;
        float gi  = acc[mf][0][v] + bia[0];
        float go  = acc[mf][3][v] + bia[3];
        float gu  = acc[mf][4][v] + bia[4];
        float cc = sigf(gi)*tanh_fast(gu);
        float hh = sigf(go)*tanh_fast(cc);
        int b = rr >> 8;
        int t2 = rr & 255;
        out[((size_t)b*TOUT + t2)*HH + jg] = hh;
        hout[(size_t)rr*HH + jg] = __float2bfloat16(hh);
        cout[(size_t)rr*HH + jg] = cc;
        acc[mf][0][v]=0.f; acc[mf][1][v]=0.f; acc[mf][2][v]=0.f;
        acc[mf][3][v]=0.f; acc[mf][4][v]=0.f;
      }
    }
  }
}

// ======== L1/L2 kernel (R7 V_A proven): BM=128, BK=32, 2x28KB, 2 blocks/CU ===
__global__ __launch_bounds__(512, 4) void gemm_cell(
    const __hip_bfloat16* __restrict__ A, const __hip_bfloat16* __restrict__ Wt,
    int K, const float* __restrict__ bias, const float* __restrict__ cprev,
    float* __restrict__ out, __hip_bfloat16* __restrict__ hout, float* __restrict__ cout,
    int lkshift, int sc, int numM)
{
  constexpr int BUFS = 28672;
  __shared__ __align__(16) char lds[2*BUFS];

  const int tid  = threadIdx.x;
  const int lane = tid & 63;
  const int wid  = tid >> 6;
  const int wm   = wid >> 2;
  const int wn   = wid & 3;
  const int bid  = blockIdx.x;
  int m, s;
  if (numM >= 8) { m = (bid & 7) + ((bid >> 6) << 3); s = (bid >> 3) & 7; }
  else           { m = bid % numM;  s = bid / numM; }
  const int r0   = m * 128;
  const int n0   = s * 64;
  const size_t rowK = (size_t)K * 2;

  const char* gsrc[4];
  int gi0 = (wid < 4) ? wid*4 : 16 + (wid-4)*3;
  #pragma unroll
  for (int i = 0; i < 4; ++i) {
    int gi = gi0 + i;
    int row = (gi < 8) ? gi*16 + (lane >> 2) : (gi-8)*16 + (lane >> 2);
    int cs = (lane & 3) ^ ((row >> 1) & 3);
    if (gi < 8) {
      gsrc[i] = (const char*)A + (size_t)(r0 + row)*rowK + cs*16;
    } else {
      int grow = (row >> 6)*512 + n0 + (row & 63);
      gsrc[i] = (const char*)Wt + (size_t)grow*rowK + cs*16;
    }
  }
  const int ldst0 = gi0*1024 + lane*16;

  f32x4 acc[4][5];
  #pragma unroll
  for (int mf = 0; mf < 4; ++mf)
    #pragma unroll
    for (int g5 = 0; g5 < 5; ++g5)
      acc[mf][g5] = (f32x4){0.f,0.f,0.f,0.f};

  const int nk = K >> 5;
  auto stage = [&](int buf, int kt){
    char* base = lds + buf*BUFS + ldst0;
    const size_t kb = (size_t)kt*64;
    if (wid < 4) {
      #pragma unroll
      for (int i = 0; i < 4; ++i) load_lds16(gsrc[i] + kb, base + i*1024);
    } else {
      #pragma unroll
      for (int i = 0; i < 3; ++i) load_lds16(gsrc[i] + kb, base + i*1024);
    }
  };

  stage(0, 0);
  int cur = 0;
  for (int kt = 0; kt < nk; ++kt) {
    if (kt + 1 < nk) {
      stage(cur ^ 1, kt + 1);
      if (wid < 4) VMWAIT(4); else VMWAIT(3);
    } else {
      VMWAIT(0);
    }
    __builtin_amdgcn_s_barrier();

    const char* Ab = lds + cur*BUFS;
    const char* Bb = Ab + 8192;
    const int q = lane >> 4;
    bf16x8 b[5];
    #pragma unroll
    for (int g5 = 0; g5 < 5; ++g5) {
      int c = g5*64 + wn*16 + (lane & 15);
      b[g5] = *(const bf16x8*)(Bb + c*64 + ((q ^ ((c >> 1) & 3))*16));
    }
    __builtin_amdgcn_s_setprio(1);
    #pragma unroll
    for (int mf = 0; mf < 4; ++mf) {
      int r = wm*64 + mf*16 + (lane & 15);
      bf16x8 av = *(const bf16x8*)(Ab + r*64 + ((q ^ ((r >> 1) & 3))*16));
      #pragma unroll
      for (int g5 = 0; g5 < 5; ++g5)
        acc[mf][g5] = __builtin_amdgcn_mfma_f32_16x16x32_bf16(av, b[g5], acc[mf][g5], 0, 0, 0);
    }
    __builtin_amdgcn_s_setprio(0);
    __builtin_amdgcn_s_barrier();
    cur ^= 1;
  }

  const int Lmask = (1 << lkshift) - 1;
  const int jg = n0 + wn*16 + (lane & 15);
  float bia[5];
  #pragma unroll
  for (int g5 = 0; g5 < 5; ++g5) bia[g5] = bias[g5*HH + jg];
  #pragma unroll
  for (int mf = 0; mf < 4; ++mf) {
    #pragma unroll
    for (int v = 0; v < 4; ++v) {
      int rr = r0 + wm*64 + mf*16 + (lane >> 4)*4 + v;
      float gi  = acc[mf][0][v] + bia[0];
      float gfl = acc[mf][1][v] + bia[1];
      float gfr = acc[mf][2][v] + bia[2];
      float go  = acc[mf][3][v] + bia[3];
      float gu  = acc[mf][4][v] + bia[4];
      float cl = cprev[(size_t)(2*rr)*HH + jg];
      float cr = cprev[(size_t)(2*rr)*HH + HH + jg];
      float cc = sigf(gi)*tanh_fast(gu) + sigf(gfl)*cl + sigf(gfr)*cr;
      float hh = sigf(go)*tanh_fast(cc);
      int b = rr >> lkshift;
      int t = rr & Lmask;
      out[((size_t)b*TOUT + sc + t)*HH + jg] = hh;
      hout[(size_t)rr*HH + jg] = __float2bfloat16(hh);
      cout[(size_t)rr*HH + jg] = cc;
    }
  }
}

// ======== TAIL kernel (L3-L8, R13 proven): BM=128, BK=64, 2x56KB dbuf ========
__global__ __launch_bounds__(512, 2) void gemm_tail(
    const __hip_bfloat16* __restrict__ A, const __hip_bfloat16* __restrict__ Wt,
    const float* __restrict__ bias, const float* __restrict__ cprev,
    float* __restrict__ out, __hip_bfloat16* __restrict__ hout, float* __restrict__ cout,
    int lkshift, int sc, int numM)
{
  constexpr int ABYTES = 16384;
  constexpr int BUFS   = ABYTES + 40960;
  __shared__ __align__(16) char lds[2*BUFS];

  const int tid  = threadIdx.x;
  const int lane = tid & 63;
  const int wid  = tid >> 6;
  const int wm   = wid >> 2;
  const int wn   = wid & 3;
  const int bid  = blockIdx.x;
  int m, s;
  if (numM >= 8) { m = (bid & 7) + ((bid >> 6) << 3); s = (bid >> 3) & 7; }
  else           { m = bid % numM;  s = bid / numM; }
  const int r0   = m * 128;
  const int n0   = s * 64;
  constexpr size_t rowK = 2048;

  const int srow = lane >> 3;
  const int gq   = (lane & 7) ^ srow;
  const char* gsrc[7];
  #pragma unroll
  for (int ii = 0; ii < 7; ++ii) {
    int issue = wid*7 + ii;
    if (issue < 16) {
      int r = issue*8 + srow;
      gsrc[ii] = (const char*)A + (size_t)(r0 + r)*rowK + (size_t)gq*16;
    } else {
      int c = (issue-16)*8 + srow;
      int grow = (c >> 6)*512 + n0 + (c & 63);
      gsrc[ii] = (const char*)Wt + (size_t)grow*rowK + (size_t)gq*16;
    }
  }
  const int ldst0 = (wid*7)*1024 + lane*16;

  f32x4 acc[4][5];
  #pragma unroll
  for (int mf = 0; mf < 4; ++mf)
    #pragma unroll
    for (int g5 = 0; g5 < 5; ++g5)
      acc[mf][g5] = (f32x4){0.f,0.f,0.f,0.f};

  auto stage = [&](int buf, int kt){
    char* base = lds + buf*BUFS + ldst0;
    const size_t kb = (size_t)kt*128;
    #pragma unroll
    for (int ii = 0; ii < 7; ++ii) load_lds16(gsrc[ii] + kb, base + ii*1024);
  };

  stage(0, 0);
  int cur = 0;
  for (int kt = 0; kt < 16; ++kt) {
    if (kt + 1 < 16) {
      stage(cur ^ 1, kt + 1);
      VMWAIT(7);
    } else {
      VMWAIT(0);
    }
    __builtin_amdgcn_s_barrier();

    const char* Ab = lds + cur*BUFS;
    const char* Bb = Ab + ABYTES;
    #pragma unroll
    for (int s2 = 0; s2 < 2; ++s2) {
      const int qb = s2*4 + (lane >> 4);
      bf16x8 b[5];
      #pragma unroll
      for (int g5 = 0; g5 < 5; ++g5) {
        int c = g5*64 + wn*16 + (lane & 15);
        b[g5] = *(const bf16x8*)(Bb + c*128 + ((qb ^ (c & 7))*16));
      }
      __builtin_amdgcn_s_setprio(1);
      #pragma unroll
      for (int mf = 0; mf < 4; ++mf) {
        int r = wm*64 + mf*16 + (lane & 15);
        bf16x8 av = *(const bf16x8*)(Ab + r*128 + ((qb ^ (r & 7))*16));
        #pragma unroll
        for (int g5 = 0; g5 < 5; ++g5)
          acc[mf][g5] = __builtin_amdgcn_mfma_f32_16x16x32_bf16(av, b[g5], acc[mf][g5], 0, 0, 0);
      }
      __builtin_amdgcn_s_setprio(0);
    }
    __builtin_amdgcn_s_barrier();
    cur ^= 1;
  }

  const int Lmask = (1 << lkshift) - 1;
  const int jg = n0 + wn*16 + (lane & 15);
  float bia[5];
  #pragma unroll
  for (int g5 = 0; g5 < 5; ++g5) bia[g5] = bias[g5*HH + jg];
  #pragma unroll
  for (int mf = 0; mf < 4; ++mf) {
    #pragma unroll
    for (int v = 0; v < 4; ++v) {
      int rr = r0 + wm*64 + mf*16 + (lane >> 4)*4 + v;
      float gi  = acc[mf][0][v] + bia[0];
      float gfl = acc[mf][1][v] + bia[1];
      float gfr = acc[mf][2][v] + bia[2];
      float go  = acc[mf][3][v] + bia[3];
      float gu  = acc[mf][4][v] + bia[4];
      float cl = cprev[(size_t)(2*rr)*HH + jg];
      float cr = cprev[(size_t)(2*rr)*HH + HH + jg];
      float cc = sigf(gi)*tanh_fast(gu) + sigf(gfl)*cl + sigf(gfr)*cr;
      float hh = sigf(go)*tanh_fast(cc);
      int b = rr >> lkshift;
      int t = rr & Lmask;
      out[((size_t)b*TOUT + sc + t)*HH + jg] = hh;
      hout[(size_t)rr*HH + jg] = __float2bfloat16(hh);
      cout[(size_t)rr*HH + jg] = cc;
    }
  }
}

extern "C" void kernel_launch(void* const* d_in, const int* in_sizes, int n_in,
                              void* d_out, int out_size, void* d_ws, size_t ws_size,
                              hipStream_t stream) {
  (void)in_sizes; (void)n_in; (void)out_size; (void)ws_size;
  const int*   tok  = (const int*)d_in[0];
  const float* emb  = (const float*)d_in[1];
  const float* Wx   = (const float*)d_in[2];
  const float* Ul   = (const float*)d_in[3];
  const float* Ur   = (const float*)d_in[4];
  const float* bias = (const float*)d_in[5];
  float* out = (float*)d_out;

  char* ws = (char*)d_ws;
  size_t off = 0;
  __hip_bfloat16* Wb0t = (__hip_bfloat16*)(ws + off); off += (size_t)NGATE*320*2;
  __hip_bfloat16* Wb1t = (__hip_bfloat16*)(ws + off); off += (size_t)NGATE*1024*2;
  __hip_bfloat16* hA   = (__hip_bfloat16*)(ws + off); off += (size_t)32768*HH*2;
  __hip_bfloat16* hB   = (__hip_bfloat16*)(ws + off); off += (size_t)16384*HH*2;
  float*          cA   = (float*)(ws + off);          off += (size_t)32768*HH*4;
  float*          cB   = (float*)(ws + off);          off += (size_t)16384*HH*4;
  __hip_bfloat16* A0   = (__hip_bfloat16*)cB;   // alias: A0 dead before cB first written

  prep_weights<<<dim3(8, 40, 3), 256, 0, stream>>>(Wx, Ul, Ur, Wb0t, Wb1t);
  embed_cvt<<<(32768*40)/256, 256, 0, stream>>>(tok, emb, A0);

  // level 0: persistent-panel kernel (256 blocks, 1/CU) — best measured (~93us)
  gemm_l0<<<256, 512, 0, stream>>>(A0, Wb0t, bias, out, hA, cA);
  // levels 1-2: R7 gemm_cell, 2 blocks/CU — best measured L1 (~113us)
  gemm_cell<<<(16384/128)*8, 512, 0, stream>>>(hA, Wb1t, 1024, bias, cA,
                                               out, hB, cB, 7, 256, 16384/128);
  gemm_cell<<<(8192/128)*8, 512, 0, stream>>>(hB, Wb1t, 1024, bias, cB,
                                              out, hA, cA, 6, 384, 8192/128);
  // levels 3..8: R13 BK=64 tail — best measured tail (~107us)
  for (int k = 3; k <= 8; ++k) {
    int M = 32768 >> k;
    int sc = HH - (HH >> k);
    const __hip_bfloat16* Ain = (k & 1) ? hA : hB;
    __hip_bfloat16*       hO  = (k & 1) ? hB : hA;
    const float*          cI  = (k & 1) ? cA : cB;
    float*                cO  = (k & 1) ? cB : cA;
    int numM = M / 128;
    gemm_tail<<<numM*8, 512, 0, stream>>>(Ain, Wb1t, bias, cI,
                                          out, hO, cO, 8 - k, sc, numM);
  }
}